// Round 6
// baseline (447.593 us; speedup 1.0000x reference)
//
#include <hip/hip_runtime.h>
#include <hip/hip_bf16.h>

#define N_NODES 50000
#define E_EDGES 800000
#define F_DIM 128
#define D_DIM 32
#define CUTOFF 5.0f
#define PI_F 3.14159265358979f
#define SCAN_BLOCKS ((N_NODES + 255) / 256)   // 196

#define MLP_ROWBLOCKS 782                      // ceil(50000/64)
#define MLP_BLOCKS (MLP_ROWBLOCKS * 2)         // x2 branches
#define HIST_BLOCKS ((E_EDGES + 511) / 512)    // 1563
#define XPAD 129                               // 128+1: all sX access <=2-way

__device__ __forceinline__ float swishf(float x) { return x / (1.0f + expf(-x)); }

// ---------------------------------------------------------------------------
// Fused: node MLP (blocks [0, MLP_BLOCKS)) + edge histogram (rest).
// MLP: block 512 = 8 waves, lane = row (64 rows/block, staged in LDS pad-129).
// Wave w: layer-1 cols 16w..16w+15; weights stream from global (L2-hot,
// vmcnt-pipelined); x via ds_read (in-order lgkm, 2-way-free). h overlays sX.
// Layer 2: wave w does cols 4w..4w+3. Output qq[row*64 + 2c + br].
// ---------------------------------------------------------------------------
__global__ __launch_bounds__(512)
void mlp_hist(const float* __restrict__ x,
              const float* __restrict__ W1a, const float* __restrict__ b1a,
              const float* __restrict__ W2a, const float* __restrict__ b2a,
              const float* __restrict__ W1b, const float* __restrict__ b1b,
              const float* __restrict__ W2b, const float* __restrict__ b2b,
              float* __restrict__ qq,
              const float* __restrict__ rij, const int* __restrict__ dst,
              int* __restrict__ deg) {
  if (blockIdx.x >= MLP_BLOCKS) {
    // ---- histogram part ----
    const int e = (blockIdx.x - MLP_BLOCKS) * 512 + threadIdx.x;
    if (e < E_EDGES && rij[e] < CUTOFF) atomicAdd(&deg[dst[e]], 1);
    return;
  }

  __shared__ float sX[64 * XPAD];   // 33 KB; x tile, then h tile (overlay)

  const int bid = blockIdx.x;
  const int br  = (bid >= MLP_ROWBLOCKS) ? 1 : 0;
  const int rb  = (bid - br * MLP_ROWBLOCKS) * 64;

  const float* __restrict__ W1 = br ? W1b : W1a;
  const float* __restrict__ b1 = br ? b1b : b1a;
  const float* __restrict__ W2 = br ? W2b : W2a;
  const float* __restrict__ b2 = br ? b2b : b2a;

  const int t = threadIdx.x;
  const int l = t & 63;        // lane = row
  const int w = t >> 6;        // wave id 0..7

  // ---- stage x[rb..rb+63][0..127] -> sX (coalesced 128B segments) ----
  {
    const int row = t >> 3;            // 0..63
    const int kq  = t & 7;             // 0..7
    const int rowG = min(rb + row, N_NODES - 1);
    const float* xp = x + (size_t)rowG * F_DIM;
#pragma unroll
    for (int p = 0; p < 4; ++p) {
      const int k0 = kq * 4 + p * 32;
      const float4 v = *(const float4*)&xp[k0];
      float* dstp = &sX[row * XPAD + k0];
      dstp[0] = v.x; dstp[1] = v.y; dstp[2] = v.z; dstp[3] = v.w;
    }
  }
  __syncthreads();

  // ---- layer 1: wave w -> cols c0..c0+15 ----
  const int c0 = w * 16;
  float acc[16];
#pragma unroll
  for (int j = 0; j < 16; ++j) acc[j] = b1[c0 + j];

  {
    const float* xl = &sX[l * XPAD];
#pragma unroll 4
    for (int k = 0; k < F_DIM; ++k) {
      const float xv = xl[k];
      const float4* wp = (const float4*)(W1 + (size_t)k * F_DIM + c0);
      const float4 w0 = wp[0], w1 = wp[1], w2 = wp[2], w3 = wp[3];
      acc[0]  = fmaf(xv, w0.x, acc[0]);  acc[1]  = fmaf(xv, w0.y, acc[1]);
      acc[2]  = fmaf(xv, w0.z, acc[2]);  acc[3]  = fmaf(xv, w0.w, acc[3]);
      acc[4]  = fmaf(xv, w1.x, acc[4]);  acc[5]  = fmaf(xv, w1.y, acc[5]);
      acc[6]  = fmaf(xv, w1.z, acc[6]);  acc[7]  = fmaf(xv, w1.w, acc[7]);
      acc[8]  = fmaf(xv, w2.x, acc[8]);  acc[9]  = fmaf(xv, w2.y, acc[9]);
      acc[10] = fmaf(xv, w2.z, acc[10]); acc[11] = fmaf(xv, w2.w, acc[11]);
      acc[12] = fmaf(xv, w3.x, acc[12]); acc[13] = fmaf(xv, w3.y, acc[13]);
      acc[14] = fmaf(xv, w3.z, acc[14]); acc[15] = fmaf(xv, w3.w, acc[15]);
    }
  }
#pragma unroll
  for (int j = 0; j < 16; ++j) acc[j] = swishf(acc[j]);

  __syncthreads();   // all waves done reading sX as x
#pragma unroll
  for (int j = 0; j < 16; ++j) sX[l * XPAD + c0 + j] = acc[j];  // h overlay
  __syncthreads();

  // ---- layer 2: wave w -> cols 4w..4w+3 ----
  const int c2 = w * 4;
  float a2v[4];
#pragma unroll
  for (int j = 0; j < 4; ++j) a2v[j] = b2[c2 + j];
  {
    const float* hl = &sX[l * XPAD];
#pragma unroll 4
    for (int k = 0; k < F_DIM; ++k) {
      const float hv = hl[k];
      const float4 wv = *(const float4*)(W2 + (size_t)k * D_DIM + c2);
      a2v[0] = fmaf(hv, wv.x, a2v[0]);
      a2v[1] = fmaf(hv, wv.y, a2v[1]);
      a2v[2] = fmaf(hv, wv.z, a2v[2]);
      a2v[3] = fmaf(hv, wv.w, a2v[3]);
    }
  }
  const int row = rb + l;
  if (row < N_NODES) {
#pragma unroll
    for (int j = 0; j < 4; ++j)
      qq[(size_t)row * 64 + 2 * (c2 + j) + br] = swishf(a2v[j]);
  }
}

// --- 3-phase coalesced scan over deg[N] -> row_start[N+1], cursor[N] ---
__global__ __launch_bounds__(256)
void scan_blocksum(const int* __restrict__ deg, int* __restrict__ part) {
  __shared__ int red[256];
  const int t = threadIdx.x;
  const int i = blockIdx.x * 256 + t;
  red[t] = (i < N_NODES) ? deg[i] : 0;
  __syncthreads();
#pragma unroll
  for (int off = 128; off > 0; off >>= 1) {
    if (t < off) red[t] += red[t + off];
    __syncthreads();
  }
  if (t == 0) part[blockIdx.x] = red[0];
}

__global__ __launch_bounds__(256)
void scan_partials(int* __restrict__ part, int* __restrict__ row_start) {
  __shared__ int s[256];
  const int t = threadIdx.x;
  const int v = (t < SCAN_BLOCKS) ? part[t] : 0;
  s[t] = v;
  __syncthreads();
  for (int off = 1; off < 256; off <<= 1) {
    const int u = (t >= off) ? s[t - off] : 0;
    __syncthreads();
    s[t] += u;
    __syncthreads();
  }
  if (t < SCAN_BLOCKS) part[t] = s[t] - v;          // exclusive block offset
  if (t == 255) row_start[N_NODES] = s[255];        // grand total
}

__global__ __launch_bounds__(256)
void scan_write(const int* __restrict__ deg, const int* __restrict__ part,
                int* __restrict__ row_start, int* __restrict__ cursor) {
  __shared__ int s[256];
  const int t = threadIdx.x;
  const int i = blockIdx.x * 256 + t;
  const int v = (i < N_NODES) ? deg[i] : 0;
  s[t] = v;
  __syncthreads();
  for (int off = 1; off < 256; off <<= 1) {
    const int u = (t >= off) ? s[t - off] : 0;
    __syncthreads();
    s[t] += u;
    __syncthreads();
  }
  const int excl = s[t] - v + part[blockIdx.x];
  if (i < N_NODES) { row_start[i] = excl; cursor[i] = excl; }
}

// Reorder surviving edges into per-dst contiguous records:
// rec = (c*vx, c*vy, c*vz, bitcast(src))
__global__ __launch_bounds__(256)
void edge_reorder(const float* __restrict__ rij, const float* __restrict__ vij,
                  const int* __restrict__ src, const int* __restrict__ dst,
                  int* __restrict__ cursor, float4* __restrict__ recs) {
  const int e = blockIdx.x * 256 + threadIdx.x;
  if (e >= E_EDGES) return;
  const float r = rij[e];
  if (r >= CUTOFF) return;
  const float c = 0.5f * (cosf(r * (PI_F / CUTOFF)) + 1.0f);
  const int pos = atomicAdd(&cursor[dst[e]], 1);
  recs[pos] = make_float4(c * vij[3 * e + 0], c * vij[3 * e + 1],
                          c * vij[3 * e + 2], __int_as_float(src[e]));
}

// ---------------------------------------------------------------------------
// Gather + cross + mix: 32 lanes per node (one per d). 4-edge batches to
// break the rec->q dependent-load chain; qq is (q,q2) interleaved float2.
// ---------------------------------------------------------------------------
__global__ __launch_bounds__(256)
void gather_out(const int* __restrict__ row_start, const float4* __restrict__ recs,
                const float2* __restrict__ qq,
                const float* __restrict__ w_mix, const float* __restrict__ b_mix,
                float* __restrict__ out) {
  const int tid = blockIdx.x * 256 + threadIdx.x;  // = n*32 + d
  const int n = tid >> 5;
  const int d = tid & 31;
  if (n >= N_NODES) return;

  const int s0 = row_start[n];
  const int s1 = row_start[n + 1];

  float ax = 0.f, ay = 0.f, az = 0.f, bx = 0.f, by = 0.f, bz = 0.f;
  for (int i = s0; i < s1; i += 4) {
    const int i1 = min(i + 1, s1 - 1);
    const int i2 = min(i + 2, s1 - 1);
    const int i3 = min(i + 3, s1 - 1);
    float4 rc0 = recs[i];
    float4 rc1 = recs[i1];
    float4 rc2 = recs[i2];
    float4 rc3 = recs[i3];
    float2 p0 = qq[__float_as_int(rc0.w) * 32 + d];
    float2 p1 = qq[__float_as_int(rc1.w) * 32 + d];
    float2 p2 = qq[__float_as_int(rc2.w) * 32 + d];
    float2 p3 = qq[__float_as_int(rc3.w) * 32 + d];
    const float m1 = (i + 1 < s1) ? 1.f : 0.f;
    const float m2 = (i + 2 < s1) ? 1.f : 0.f;
    const float m3 = (i + 3 < s1) ? 1.f : 0.f;
    p1.x *= m1; p1.y *= m1;
    p2.x *= m2; p2.y *= m2;
    p3.x *= m3; p3.y *= m3;

    ax += rc0.x * p0.x + rc1.x * p1.x + rc2.x * p2.x + rc3.x * p3.x;
    ay += rc0.y * p0.x + rc1.y * p1.x + rc2.y * p2.x + rc3.y * p3.x;
    az += rc0.z * p0.x + rc1.z * p1.x + rc2.z * p2.x + rc3.z * p3.x;
    bx += rc0.x * p0.y + rc1.x * p1.y + rc2.x * p2.y + rc3.x * p3.y;
    by += rc0.y * p0.y + rc1.y * p1.y + rc2.y * p2.y + rc3.y * p3.y;
    bz += rc0.z * p0.y + rc1.z * p1.y + rc2.z * p2.y + rc3.z * p3.y;
  }

  const float cx = ay * bz - az * by;
  const float cy = az * bx - ax * bz;
  const float cz = ax * by - ay * bx;

  const float w0 = w_mix[0], w1 = w_mix[1], w2 = w_mix[2];
  const float bm = b_mix[0];

  const size_t base = (size_t)tid * 3;
  out[base + 0] = ax * w0 + bx * w1 + cx * w2 + bm;
  out[base + 1] = ay * w0 + by * w1 + cy * w2 + bm;
  out[base + 2] = az * w0 + bz * w1 + cz * w2 + bm;
}

// ---------------------------------------------------------------------------
extern "C" void kernel_launch(void* const* d_in, const int* in_sizes, int n_in,
                              void* d_out, int out_size, void* d_ws, size_t ws_size,
                              hipStream_t stream) {
  const float* x     = (const float*)d_in[0];
  const float* rij   = (const float*)d_in[1];
  const float* vij   = (const float*)d_in[2];
  const int*   src   = (const int*)  d_in[3];
  const int*   dst   = (const int*)  d_in[4];
  const float* W1    = (const float*)d_in[5];
  const float* b1    = (const float*)d_in[6];
  const float* W2    = (const float*)d_in[7];
  const float* b2    = (const float*)d_in[8];
  const float* W1b   = (const float*)d_in[9];
  const float* b1b   = (const float*)d_in[10];
  const float* W2b   = (const float*)d_in[11];
  const float* b2b   = (const float*)d_in[12];
  const float* w_mix = (const float*)d_in[13];
  const float* b_mix = (const float*)d_in[14];
  float* out = (float*)d_out;

  // Workspace: recs [E f4] | qq [N*64] | deg [N] | cursor [N] | row_start [N+1] | part [256]
  float4* recs   = (float4*)d_ws;
  float* qq      = (float*)(recs + E_EDGES);
  int* deg       = (int*)(qq + (size_t)N_NODES * 64);
  int* cursor    = deg + N_NODES;
  int* row_start = cursor + N_NODES;
  int* part      = row_start + N_NODES + 1;

  hipMemsetAsync(deg, 0, sizeof(int) * N_NODES, stream);

  mlp_hist<<<MLP_BLOCKS + HIST_BLOCKS, 512, 0, stream>>>(
      x, W1, b1, W2, b2, W1b, b1b, W2b, b2b, qq, rij, dst, deg);

  scan_blocksum<<<SCAN_BLOCKS, 256, 0, stream>>>(deg, part);
  scan_partials<<<1, 256, 0, stream>>>(part, row_start);
  scan_write<<<SCAN_BLOCKS, 256, 0, stream>>>(deg, part, row_start, cursor);

  const int eb = (E_EDGES + 255) / 256;
  edge_reorder<<<eb, 256, 0, stream>>>(rij, vij, src, dst, cursor, recs);

  gather_out<<<(N_NODES * D_DIM) / 256, 256, 0, stream>>>(
      row_start, recs, (const float2*)qq, w_mix, b_mix, out);
}

// Round 7
// 447.207 us; speedup vs baseline: 1.0009x; 1.0009x over previous
//
#include <hip/hip_runtime.h>
#include <hip/hip_bf16.h>

#define N_NODES 50000
#define E_EDGES 800000
#define F_DIM 128
#define D_DIM 32
#define CUTOFF 5.0f
#define PI_F 3.14159265358979f
#define SCAN_BLOCKS ((N_NODES + 255) / 256)   // 196

#define MLP_ROWBLOCKS 782                      // ceil(50000/64)
#define MLP_BLOCKS (MLP_ROWBLOCKS * 2)         // x2 branches
#define HIST_BLOCKS ((E_EDGES + 511) / 512)    // 1563
#define XPAD 132   // 128+4: float4-aligned rows; stride-132 b128 = conflict-free

__device__ __forceinline__ float swishf(float x) { return x / (1.0f + expf(-x)); }

// ---------------------------------------------------------------------------
// Fused: node MLP (blocks [0, MLP_BLOCKS)) + edge histogram (rest).
// MLP: block 512 = 8 waves, lane = row (64 rows/block in LDS, pad 132).
// Wave w: layer-1 cols 16w..16w+15; weights stream from global (L2-hot,
// vmcnt-pipelined); x via ds_read_b128. h overlays sX. Layer 2: cols 4w..4w+3.
// __launch_bounds__(512,4): VGPR cap 128 — R6's 32-VGPR allocation serialized
// the weight loads (VALUBusy 14.6%); the cap is the fix, do not remove.
// ---------------------------------------------------------------------------
__global__ __launch_bounds__(512, 4)
void mlp_hist(const float* __restrict__ x,
              const float* __restrict__ W1a, const float* __restrict__ b1a,
              const float* __restrict__ W2a, const float* __restrict__ b2a,
              const float* __restrict__ W1b, const float* __restrict__ b1b,
              const float* __restrict__ W2b, const float* __restrict__ b2b,
              float* __restrict__ qq,
              const float* __restrict__ rij, const int* __restrict__ dst,
              int* __restrict__ deg) {
  if (blockIdx.x >= MLP_BLOCKS) {
    // ---- histogram part ----
    const int e = (blockIdx.x - MLP_BLOCKS) * 512 + threadIdx.x;
    if (e < E_EDGES && rij[e] < CUTOFF) atomicAdd(&deg[dst[e]], 1);
    return;
  }

  __shared__ float sX[64 * XPAD];   // 33 KB; x tile, then h tile (overlay)

  const int bid = blockIdx.x;
  const int br  = (bid >= MLP_ROWBLOCKS) ? 1 : 0;
  const int rb  = (bid - br * MLP_ROWBLOCKS) * 64;

  const float* __restrict__ W1 = br ? W1b : W1a;
  const float* __restrict__ b1 = br ? b1b : b1a;
  const float* __restrict__ W2 = br ? W2b : W2a;
  const float* __restrict__ b2 = br ? b2b : b2a;

  const int t = threadIdx.x;
  const int l = t & 63;        // lane = row
  const int w = t >> 6;        // wave id 0..7

  // ---- stage x[rb..rb+63][0..127] -> sX (coalesced 128B segments) ----
  {
    const int row = t >> 3;            // 0..63
    const int kq  = t & 7;             // 0..7
    const int rowG = min(rb + row, N_NODES - 1);
    const float* xp = x + (size_t)rowG * F_DIM;
#pragma unroll
    for (int p = 0; p < 4; ++p) {
      const int k0 = kq * 4 + p * 32;
      *(float4*)&sX[row * XPAD + k0] = *(const float4*)&xp[k0];
    }
  }
  __syncthreads();

  // ---- layer 1: wave w -> cols c0..c0+15 ----
  const int c0 = w * 16;
  float acc[16];
#pragma unroll
  for (int j = 0; j < 16; ++j) acc[j] = b1[c0 + j];

  {
    const float* xl = &sX[l * XPAD];
    for (int k4 = 0; k4 < 32; ++k4) {
      const float4 xv = *(const float4*)&xl[k4 * 4];   // ds_read_b128
#pragma unroll
      for (int j = 0; j < 4; ++j) {
        const float4* wp = (const float4*)(W1 + (size_t)(k4 * 4 + j) * F_DIM + c0);
        const float4 w0 = wp[0], w1 = wp[1], w2 = wp[2], w3 = wp[3];
        const float xs = (j == 0) ? xv.x : (j == 1) ? xv.y : (j == 2) ? xv.z : xv.w;
        acc[0]  = fmaf(xs, w0.x, acc[0]);  acc[1]  = fmaf(xs, w0.y, acc[1]);
        acc[2]  = fmaf(xs, w0.z, acc[2]);  acc[3]  = fmaf(xs, w0.w, acc[3]);
        acc[4]  = fmaf(xs, w1.x, acc[4]);  acc[5]  = fmaf(xs, w1.y, acc[5]);
        acc[6]  = fmaf(xs, w1.z, acc[6]);  acc[7]  = fmaf(xs, w1.w, acc[7]);
        acc[8]  = fmaf(xs, w2.x, acc[8]);  acc[9]  = fmaf(xs, w2.y, acc[9]);
        acc[10] = fmaf(xs, w2.z, acc[10]); acc[11] = fmaf(xs, w2.w, acc[11]);
        acc[12] = fmaf(xs, w3.x, acc[12]); acc[13] = fmaf(xs, w3.y, acc[13]);
        acc[14] = fmaf(xs, w3.z, acc[14]); acc[15] = fmaf(xs, w3.w, acc[15]);
      }
    }
  }
#pragma unroll
  for (int j = 0; j < 16; ++j) acc[j] = swishf(acc[j]);

  __syncthreads();   // all waves done reading sX as x
#pragma unroll
  for (int j4 = 0; j4 < 4; ++j4)     // h overlay, ds_write_b128
    *(float4*)&sX[l * XPAD + c0 + 4 * j4] =
        make_float4(acc[4 * j4], acc[4 * j4 + 1], acc[4 * j4 + 2], acc[4 * j4 + 3]);
  __syncthreads();

  // ---- layer 2: wave w -> cols 4w..4w+3 ----
  const int c2 = w * 4;
  float a0 = b2[c2], a1 = b2[c2 + 1], a2v = b2[c2 + 2], a3 = b2[c2 + 3];
  {
    const float* hl = &sX[l * XPAD];
    for (int k4 = 0; k4 < 32; ++k4) {
      const float4 hv = *(const float4*)&hl[k4 * 4];   // ds_read_b128
#pragma unroll
      for (int j = 0; j < 4; ++j) {
        const float4 wv = *(const float4*)(W2 + (size_t)(k4 * 4 + j) * D_DIM + c2);
        const float hs = (j == 0) ? hv.x : (j == 1) ? hv.y : (j == 2) ? hv.z : hv.w;
        a0  = fmaf(hs, wv.x, a0);
        a1  = fmaf(hs, wv.y, a1);
        a2v = fmaf(hs, wv.z, a2v);
        a3  = fmaf(hs, wv.w, a3);
      }
    }
  }
  const int row = rb + l;
  if (row < N_NODES) {
    qq[(size_t)row * 64 + 2 * (c2 + 0) + br] = swishf(a0);
    qq[(size_t)row * 64 + 2 * (c2 + 1) + br] = swishf(a1);
    qq[(size_t)row * 64 + 2 * (c2 + 2) + br] = swishf(a2v);
    qq[(size_t)row * 64 + 2 * (c2 + 3) + br] = swishf(a3);
  }
}

// --- 3-phase coalesced scan over deg[N] -> row_start[N+1], cursor[N] ---
__global__ __launch_bounds__(256)
void scan_blocksum(const int* __restrict__ deg, int* __restrict__ part) {
  __shared__ int red[256];
  const int t = threadIdx.x;
  const int i = blockIdx.x * 256 + t;
  red[t] = (i < N_NODES) ? deg[i] : 0;
  __syncthreads();
#pragma unroll
  for (int off = 128; off > 0; off >>= 1) {
    if (t < off) red[t] += red[t + off];
    __syncthreads();
  }
  if (t == 0) part[blockIdx.x] = red[0];
}

__global__ __launch_bounds__(256)
void scan_partials(int* __restrict__ part, int* __restrict__ row_start) {
  __shared__ int s[256];
  const int t = threadIdx.x;
  const int v = (t < SCAN_BLOCKS) ? part[t] : 0;
  s[t] = v;
  __syncthreads();
  for (int off = 1; off < 256; off <<= 1) {
    const int u = (t >= off) ? s[t - off] : 0;
    __syncthreads();
    s[t] += u;
    __syncthreads();
  }
  if (t < SCAN_BLOCKS) part[t] = s[t] - v;          // exclusive block offset
  if (t == 255) row_start[N_NODES] = s[255];        // grand total
}

__global__ __launch_bounds__(256)
void scan_write(const int* __restrict__ deg, const int* __restrict__ part,
                int* __restrict__ row_start, int* __restrict__ cursor) {
  __shared__ int s[256];
  const int t = threadIdx.x;
  const int i = blockIdx.x * 256 + t;
  const int v = (i < N_NODES) ? deg[i] : 0;
  s[t] = v;
  __syncthreads();
  for (int off = 1; off < 256; off <<= 1) {
    const int u = (t >= off) ? s[t - off] : 0;
    __syncthreads();
    s[t] += u;
    __syncthreads();
  }
  const int excl = s[t] - v + part[blockIdx.x];
  if (i < N_NODES) { row_start[i] = excl; cursor[i] = excl; }
}

// Reorder surviving edges into per-dst contiguous records:
// rec = (c*vx, c*vy, c*vz, bitcast(src))
__global__ __launch_bounds__(256)
void edge_reorder(const float* __restrict__ rij, const float* __restrict__ vij,
                  const int* __restrict__ src, const int* __restrict__ dst,
                  int* __restrict__ cursor, float4* __restrict__ recs) {
  const int e = blockIdx.x * 256 + threadIdx.x;
  if (e >= E_EDGES) return;
  const float r = rij[e];
  if (r >= CUTOFF) return;
  const float c = 0.5f * (cosf(r * (PI_F / CUTOFF)) + 1.0f);
  const int pos = atomicAdd(&cursor[dst[e]], 1);
  recs[pos] = make_float4(c * vij[3 * e + 0], c * vij[3 * e + 1],
                          c * vij[3 * e + 2], __int_as_float(src[e]));
}

// ---------------------------------------------------------------------------
// Gather + cross + mix: 32 lanes per node (one per d). 4-edge batches to
// break the rec->q dependent-load chain; qq is (q,q2) interleaved float2.
// ---------------------------------------------------------------------------
__global__ __launch_bounds__(256)
void gather_out(const int* __restrict__ row_start, const float4* __restrict__ recs,
                const float2* __restrict__ qq,
                const float* __restrict__ w_mix, const float* __restrict__ b_mix,
                float* __restrict__ out) {
  const int tid = blockIdx.x * 256 + threadIdx.x;  // = n*32 + d
  const int n = tid >> 5;
  const int d = tid & 31;
  if (n >= N_NODES) return;

  const int s0 = row_start[n];
  const int s1 = row_start[n + 1];

  float ax = 0.f, ay = 0.f, az = 0.f, bx = 0.f, by = 0.f, bz = 0.f;
  for (int i = s0; i < s1; i += 4) {
    const int i1 = min(i + 1, s1 - 1);
    const int i2 = min(i + 2, s1 - 1);
    const int i3 = min(i + 3, s1 - 1);
    float4 rc0 = recs[i];
    float4 rc1 = recs[i1];
    float4 rc2 = recs[i2];
    float4 rc3 = recs[i3];
    float2 p0 = qq[__float_as_int(rc0.w) * 32 + d];
    float2 p1 = qq[__float_as_int(rc1.w) * 32 + d];
    float2 p2 = qq[__float_as_int(rc2.w) * 32 + d];
    float2 p3 = qq[__float_as_int(rc3.w) * 32 + d];
    const float m1 = (i + 1 < s1) ? 1.f : 0.f;
    const float m2 = (i + 2 < s1) ? 1.f : 0.f;
    const float m3 = (i + 3 < s1) ? 1.f : 0.f;
    p1.x *= m1; p1.y *= m1;
    p2.x *= m2; p2.y *= m2;
    p3.x *= m3; p3.y *= m3;

    ax += rc0.x * p0.x + rc1.x * p1.x + rc2.x * p2.x + rc3.x * p3.x;
    ay += rc0.y * p0.x + rc1.y * p1.x + rc2.y * p2.x + rc3.y * p3.x;
    az += rc0.z * p0.x + rc1.z * p1.x + rc2.z * p2.x + rc3.z * p3.x;
    bx += rc0.x * p0.y + rc1.x * p1.y + rc2.x * p2.y + rc3.x * p3.y;
    by += rc0.y * p0.y + rc1.y * p1.y + rc2.y * p2.y + rc3.y * p3.y;
    bz += rc0.z * p0.y + rc1.z * p1.y + rc2.z * p2.y + rc3.z * p3.y;
  }

  const float cx = ay * bz - az * by;
  const float cy = az * bx - ax * bz;
  const float cz = ax * by - ay * bx;

  const float w0 = w_mix[0], w1 = w_mix[1], w2 = w_mix[2];
  const float bm = b_mix[0];

  const size_t base = (size_t)tid * 3;
  out[base + 0] = ax * w0 + bx * w1 + cx * w2 + bm;
  out[base + 1] = ay * w0 + by * w1 + cy * w2 + bm;
  out[base + 2] = az * w0 + bz * w1 + cz * w2 + bm;
}

// ---------------------------------------------------------------------------
extern "C" void kernel_launch(void* const* d_in, const int* in_sizes, int n_in,
                              void* d_out, int out_size, void* d_ws, size_t ws_size,
                              hipStream_t stream) {
  const float* x     = (const float*)d_in[0];
  const float* rij   = (const float*)d_in[1];
  const float* vij   = (const float*)d_in[2];
  const int*   src   = (const int*)  d_in[3];
  const int*   dst   = (const int*)  d_in[4];
  const float* W1    = (const float*)d_in[5];
  const float* b1    = (const float*)d_in[6];
  const float* W2    = (const float*)d_in[7];
  const float* b2    = (const float*)d_in[8];
  const float* W1b   = (const float*)d_in[9];
  const float* b1b   = (const float*)d_in[10];
  const float* W2b   = (const float*)d_in[11];
  const float* b2b   = (const float*)d_in[12];
  const float* w_mix = (const float*)d_in[13];
  const float* b_mix = (const float*)d_in[14];
  float* out = (float*)d_out;

  // Workspace: recs [E f4] | qq [N*64] | deg [N] | cursor [N] | row_start [N+1] | part [256]
  float4* recs   = (float4*)d_ws;
  float* qq      = (float*)(recs + E_EDGES);
  int* deg       = (int*)(qq + (size_t)N_NODES * 64);
  int* cursor    = deg + N_NODES;
  int* row_start = cursor + N_NODES;
  int* part      = row_start + N_NODES + 1;

  hipMemsetAsync(deg, 0, sizeof(int) * N_NODES, stream);

  mlp_hist<<<MLP_BLOCKS + HIST_BLOCKS, 512, 0, stream>>>(
      x, W1, b1, W2, b2, W1b, b1b, W2b, b2b, qq, rij, dst, deg);

  scan_blocksum<<<SCAN_BLOCKS, 256, 0, stream>>>(deg, part);
  scan_partials<<<1, 256, 0, stream>>>(part, row_start);
  scan_write<<<SCAN_BLOCKS, 256, 0, stream>>>(deg, part, row_start, cursor);

  const int eb = (E_EDGES + 255) / 256;
  edge_reorder<<<eb, 256, 0, stream>>>(rij, vij, src, dst, cursor, recs);

  gather_out<<<(N_NODES * D_DIM) / 256, 256, 0, stream>>>(
      row_start, recs, (const float2*)qq, w_mix, b_mix, out);
}

// Round 8
// 297.004 us; speedup vs baseline: 1.5070x; 1.5057x over previous
//
#include <hip/hip_runtime.h>
#include <hip/hip_bf16.h>

#define N_NODES 50000
#define E_EDGES 800000
#define F_DIM 128
#define D_DIM 32
#define CUTOFF 5.0f
#define PI_F 3.14159265358979f
#define SCAN_BLOCKS ((N_NODES + 255) / 256)   // 196

#define MLP_ROWBLOCKS 1563                     // ceil(50000/32)
#define MLP_BLOCKS (MLP_ROWBLOCKS * 2)         // x2 branches
#define HIST_BLOCKS ((E_EDGES + 511) / 512)    // 1563
#define XPAD 132   // 128+4: float4-aligned rows, conflict-free b128

__device__ __forceinline__ float swishf(float x) { return x / (1.0f + expf(-x)); }

// ---------------------------------------------------------------------------
// Fused: node MLP (blocks [0, MLP_BLOCKS)) + edge histogram (rest).
// MLP: block 512 = 8 waves = (row-group rg=w&3, col-half ch=w>>2); 32 rows.
// LANE = COLUMN: weight loads are lane-varying -> global_load (vmcnt path,
// in-order, pipelined). x is the wave-uniform operand -> ds_read_b128
// broadcast (lgkm contains only in-order LDS ops).
// RULE (R5/R7 lesson): never let a hot-loop operand be wave-uniform global —
// it becomes s_load (out-of-order) and forces lgkmcnt(0) drains with ds_read.
// ---------------------------------------------------------------------------
__global__ __launch_bounds__(512, 4)
void mlp_hist(const float* __restrict__ x,
              const float* __restrict__ W1a, const float* __restrict__ b1a,
              const float* __restrict__ W2a, const float* __restrict__ b2a,
              const float* __restrict__ W1b, const float* __restrict__ b1b,
              const float* __restrict__ W2b, const float* __restrict__ b2b,
              float* __restrict__ qq,
              const float* __restrict__ rij, const int* __restrict__ dst,
              int* __restrict__ deg) {
  if (blockIdx.x >= MLP_BLOCKS) {
    // ---- histogram part ----
    const int e = (blockIdx.x - MLP_BLOCKS) * 512 + threadIdx.x;
    if (e < E_EDGES && rij[e] < CUTOFF) atomicAdd(&deg[dst[e]], 1);
    return;
  }

  __shared__ float sX[32 * XPAD];   // 16.9 KB; x tile, then h overlay

  const int bid = blockIdx.x;
  const int br  = (bid >= MLP_ROWBLOCKS) ? 1 : 0;
  const int rb  = (bid - br * MLP_ROWBLOCKS) * 32;

  const float* __restrict__ W1 = br ? W1b : W1a;
  const float* __restrict__ b1 = br ? b1b : b1a;
  const float* __restrict__ W2 = br ? W2b : W2a;
  const float* __restrict__ b2 = br ? b2b : b2a;

  const int t  = threadIdx.x;
  const int l  = t & 63;
  const int w  = t >> 6;
  const int rg = w & 3;        // row-group: rows rg*8 .. rg*8+7
  const int ch = w >> 2;       // col-half:  cols ch*64 .. ch*64+63

  // ---- stage x[rb..rb+31][0..127] -> sX (coalesced; 2 float4/thread) ----
  {
    const int row = t >> 4;            // 0..31
    const int kq  = t & 15;            // 0..15
    const int rowG = min(rb + row, N_NODES - 1);
    const float* xp = x + (size_t)rowG * F_DIM;
#pragma unroll
    for (int p = 0; p < 2; ++p) {
      const int k0 = kq * 4 + p * 64;
      *(float4*)&sX[row * XPAD + k0] = *(const float4*)&xp[k0];
    }
  }
  __syncthreads();

  // ---- layer 1: lane = col c; 8 rows/lane ----
  const int c = ch * 64 + l;               // lane-varying!
  float acc[8];
  {
    const float bc = b1[c];
#pragma unroll
    for (int r = 0; r < 8; ++r) acc[r] = bc;
  }
  {
    const float* Wc    = W1 + c;                 // stride F_DIM, lane-varying
    const float* xbase = sX + (rg * 8) * XPAD;   // wave-uniform LDS
#pragma unroll 2
    for (int k4 = 0; k4 < 32; ++k4) {
      const float w0 = Wc[(size_t)(k4 * 4 + 0) * F_DIM];
      const float w1 = Wc[(size_t)(k4 * 4 + 1) * F_DIM];
      const float w2 = Wc[(size_t)(k4 * 4 + 2) * F_DIM];
      const float w3 = Wc[(size_t)(k4 * 4 + 3) * F_DIM];
      float4 xv[8];
#pragma unroll
      for (int r = 0; r < 8; ++r)
        xv[r] = *(const float4*)&xbase[r * XPAD + k4 * 4];   // broadcast b128
#pragma unroll
      for (int r = 0; r < 8; ++r) {
        acc[r] = fmaf(xv[r].x, w0, acc[r]);
        acc[r] = fmaf(xv[r].y, w1, acc[r]);
        acc[r] = fmaf(xv[r].z, w2, acc[r]);
        acc[r] = fmaf(xv[r].w, w3, acc[r]);
      }
    }
  }

  __syncthreads();                 // everyone done reading sX as x
#pragma unroll
  for (int r = 0; r < 8; ++r)      // h overlay in place (2-way banks = free)
    sX[(rg * 8 + r) * XPAD + c] = swishf(acc[r]);
  __syncthreads();

  // ---- layer 2: lane = (c2 = l&31, rr = l>>5); wave rows rg*8+ch*4+{0..3} ----
  const int c2 = l & 31;
  const int rr = l >> 5;
  const int rowA = rg * 8 + ch * 4 + rr;      // this lane: rows rowA, rowA+2
  float a0 = b2[c2], a1 = a0;
  {
    const float* W2c = W2 + c2;                // lane-varying
    const float* hA  = sX + rowA * XPAD;
    const float* hB  = sX + (rowA + 2) * XPAD;
#pragma unroll 2
    for (int k4 = 0; k4 < 32; ++k4) {
      const float w0 = W2c[(size_t)(k4 * 4 + 0) * D_DIM];
      const float w1 = W2c[(size_t)(k4 * 4 + 1) * D_DIM];
      const float w2 = W2c[(size_t)(k4 * 4 + 2) * D_DIM];
      const float w3 = W2c[(size_t)(k4 * 4 + 3) * D_DIM];
      const float4 ha = *(const float4*)&hA[k4 * 4];
      const float4 hb = *(const float4*)&hB[k4 * 4];
      a0 = fmaf(ha.x, w0, a0); a0 = fmaf(ha.y, w1, a0);
      a0 = fmaf(ha.z, w2, a0); a0 = fmaf(ha.w, w3, a0);
      a1 = fmaf(hb.x, w0, a1); a1 = fmaf(hb.y, w1, a1);
      a1 = fmaf(hb.z, w2, a1); a1 = fmaf(hb.w, w3, a1);
    }
  }
  {
    const int g0 = rb + rowA;
    const int g1 = rb + rowA + 2;
    if (g0 < N_NODES) qq[(size_t)g0 * 64 + 2 * c2 + br] = swishf(a0);
    if (g1 < N_NODES) qq[(size_t)g1 * 64 + 2 * c2 + br] = swishf(a1);
  }
}

// --- 3-phase coalesced scan over deg[N] -> row_start[N+1], cursor[N] ---
__global__ __launch_bounds__(256)
void scan_blocksum(const int* __restrict__ deg, int* __restrict__ part) {
  __shared__ int red[256];
  const int t = threadIdx.x;
  const int i = blockIdx.x * 256 + t;
  red[t] = (i < N_NODES) ? deg[i] : 0;
  __syncthreads();
#pragma unroll
  for (int off = 128; off > 0; off >>= 1) {
    if (t < off) red[t] += red[t + off];
    __syncthreads();
  }
  if (t == 0) part[blockIdx.x] = red[0];
}

__global__ __launch_bounds__(256)
void scan_partials(int* __restrict__ part, int* __restrict__ row_start) {
  __shared__ int s[256];
  const int t = threadIdx.x;
  const int v = (t < SCAN_BLOCKS) ? part[t] : 0;
  s[t] = v;
  __syncthreads();
  for (int off = 1; off < 256; off <<= 1) {
    const int u = (t >= off) ? s[t - off] : 0;
    __syncthreads();
    s[t] += u;
    __syncthreads();
  }
  if (t < SCAN_BLOCKS) part[t] = s[t] - v;          // exclusive block offset
  if (t == 255) row_start[N_NODES] = s[255];        // grand total
}

__global__ __launch_bounds__(256)
void scan_write(const int* __restrict__ deg, const int* __restrict__ part,
                int* __restrict__ row_start, int* __restrict__ cursor) {
  __shared__ int s[256];
  const int t = threadIdx.x;
  const int i = blockIdx.x * 256 + t;
  const int v = (i < N_NODES) ? deg[i] : 0;
  s[t] = v;
  __syncthreads();
  for (int off = 1; off < 256; off <<= 1) {
    const int u = (t >= off) ? s[t - off] : 0;
    __syncthreads();
    s[t] += u;
    __syncthreads();
  }
  const int excl = s[t] - v + part[blockIdx.x];
  if (i < N_NODES) { row_start[i] = excl; cursor[i] = excl; }
}

// Reorder surviving edges into per-dst contiguous records:
// rec = (c*vx, c*vy, c*vz, bitcast(src))
__global__ __launch_bounds__(256)
void edge_reorder(const float* __restrict__ rij, const float* __restrict__ vij,
                  const int* __restrict__ src, const int* __restrict__ dst,
                  int* __restrict__ cursor, float4* __restrict__ recs) {
  const int e = blockIdx.x * 256 + threadIdx.x;
  if (e >= E_EDGES) return;
  const float r = rij[e];
  if (r >= CUTOFF) return;
  const float c = 0.5f * (cosf(r * (PI_F / CUTOFF)) + 1.0f);
  const int pos = atomicAdd(&cursor[dst[e]], 1);
  recs[pos] = make_float4(c * vij[3 * e + 0], c * vij[3 * e + 1],
                          c * vij[3 * e + 2], __int_as_float(src[e]));
}

// ---------------------------------------------------------------------------
// Gather + cross + mix: 32 lanes per node (one per d). 4-edge batches to
// break the rec->q dependent-load chain; qq is (q,q2) interleaved float2.
// ---------------------------------------------------------------------------
__global__ __launch_bounds__(256)
void gather_out(const int* __restrict__ row_start, const float4* __restrict__ recs,
                const float2* __restrict__ qq,
                const float* __restrict__ w_mix, const float* __restrict__ b_mix,
                float* __restrict__ out) {
  const int tid = blockIdx.x * 256 + threadIdx.x;  // = n*32 + d
  const int n = tid >> 5;
  const int d = tid & 31;
  if (n >= N_NODES) return;

  const int s0 = row_start[n];
  const int s1 = row_start[n + 1];

  float ax = 0.f, ay = 0.f, az = 0.f, bx = 0.f, by = 0.f, bz = 0.f;
  for (int i = s0; i < s1; i += 4) {
    const int i1 = min(i + 1, s1 - 1);
    const int i2 = min(i + 2, s1 - 1);
    const int i3 = min(i + 3, s1 - 1);
    float4 rc0 = recs[i];
    float4 rc1 = recs[i1];
    float4 rc2 = recs[i2];
    float4 rc3 = recs[i3];
    float2 p0 = qq[__float_as_int(rc0.w) * 32 + d];
    float2 p1 = qq[__float_as_int(rc1.w) * 32 + d];
    float2 p2 = qq[__float_as_int(rc2.w) * 32 + d];
    float2 p3 = qq[__float_as_int(rc3.w) * 32 + d];
    const float m1 = (i + 1 < s1) ? 1.f : 0.f;
    const float m2 = (i + 2 < s1) ? 1.f : 0.f;
    const float m3 = (i + 3 < s1) ? 1.f : 0.f;
    p1.x *= m1; p1.y *= m1;
    p2.x *= m2; p2.y *= m2;
    p3.x *= m3; p3.y *= m3;

    ax += rc0.x * p0.x + rc1.x * p1.x + rc2.x * p2.x + rc3.x * p3.x;
    ay += rc0.y * p0.x + rc1.y * p1.x + rc2.y * p2.x + rc3.y * p3.x;
    az += rc0.z * p0.x + rc1.z * p1.x + rc2.z * p2.x + rc3.z * p3.x;
    bx += rc0.x * p0.y + rc1.x * p1.y + rc2.x * p2.y + rc3.x * p3.y;
    by += rc0.y * p0.y + rc1.y * p1.y + rc2.y * p2.y + rc3.y * p3.y;
    bz += rc0.z * p0.y + rc1.z * p1.y + rc2.z * p2.y + rc3.z * p3.y;
  }

  const float cx = ay * bz - az * by;
  const float cy = az * bx - ax * bz;
  const float cz = ax * by - ay * bx;

  const float w0 = w_mix[0], w1 = w_mix[1], w2 = w_mix[2];
  const float bm = b_mix[0];

  const size_t base = (size_t)tid * 3;
  out[base + 0] = ax * w0 + bx * w1 + cx * w2 + bm;
  out[base + 1] = ay * w0 + by * w1 + cy * w2 + bm;
  out[base + 2] = az * w0 + bz * w1 + cz * w2 + bm;
}

// ---------------------------------------------------------------------------
extern "C" void kernel_launch(void* const* d_in, const int* in_sizes, int n_in,
                              void* d_out, int out_size, void* d_ws, size_t ws_size,
                              hipStream_t stream) {
  const float* x     = (const float*)d_in[0];
  const float* rij   = (const float*)d_in[1];
  const float* vij   = (const float*)d_in[2];
  const int*   src   = (const int*)  d_in[3];
  const int*   dst   = (const int*)  d_in[4];
  const float* W1    = (const float*)d_in[5];
  const float* b1    = (const float*)d_in[6];
  const float* W2    = (const float*)d_in[7];
  const float* b2    = (const float*)d_in[8];
  const float* W1b   = (const float*)d_in[9];
  const float* b1b   = (const float*)d_in[10];
  const float* W2b   = (const float*)d_in[11];
  const float* b2b   = (const float*)d_in[12];
  const float* w_mix = (const float*)d_in[13];
  const float* b_mix = (const float*)d_in[14];
  float* out = (float*)d_out;

  // Workspace: recs [E f4] | qq [N*64] | deg [N] | cursor [N] | row_start [N+1] | part [256]
  float4* recs   = (float4*)d_ws;
  float* qq      = (float*)(recs + E_EDGES);
  int* deg       = (int*)(qq + (size_t)N_NODES * 64);
  int* cursor    = deg + N_NODES;
  int* row_start = cursor + N_NODES;
  int* part      = row_start + N_NODES + 1;

  hipMemsetAsync(deg, 0, sizeof(int) * N_NODES, stream);

  mlp_hist<<<MLP_BLOCKS + HIST_BLOCKS, 512, 0, stream>>>(
      x, W1, b1, W2, b2, W1b, b1b, W2b, b2b, qq, rij, dst, deg);

  scan_blocksum<<<SCAN_BLOCKS, 256, 0, stream>>>(deg, part);
  scan_partials<<<1, 256, 0, stream>>>(part, row_start);
  scan_write<<<SCAN_BLOCKS, 256, 0, stream>>>(deg, part, row_start, cursor);

  const int eb = (E_EDGES + 255) / 256;
  edge_reorder<<<eb, 256, 0, stream>>>(rij, vij, src, dst, cursor, recs);

  gather_out<<<(N_NODES * D_DIM) / 256, 256, 0, stream>>>(
      row_start, recs, (const float2*)qq, w_mix, b_mix, out);
}

// Round 9
// 281.596 us; speedup vs baseline: 1.5895x; 1.0547x over previous
//
#include <hip/hip_runtime.h>
#include <hip/hip_bf16.h>

#define N_NODES 50000
#define E_EDGES 800000
#define F_DIM 128
#define D_DIM 32
#define CUTOFF 5.0f
#define PI_F 3.14159265358979f
#define SCAN_BLOCKS ((N_NODES + 255) / 256)   // 196

#define MLP_ROWBLOCKS 782                      // ceil(50000/64)
#define MLP_BLOCKS (MLP_ROWBLOCKS * 2)         // x2 branches
#define HIST_BLOCKS ((E_EDGES + 511) / 512)    // 1563
#define XPAD 132   // 128+4: float4-aligned rows, conflict-free b128

__device__ __forceinline__ float swishf(float x) { return x / (1.0f + expf(-x)); }

// ---------------------------------------------------------------------------
// Fused: node MLP (blocks [0, MLP_BLOCKS)) + edge histogram (rest).
// MLP: block 512 = 8 waves, 64 rows. Register blocking 4 rows x 4 cols/lane:
// per k4 = 4 ds_read_b128 + 16 coalesced weight dwords + 64 FMAs
// -> LDS bytes/FMA = 1 (R8 was 4: LDS-issue bound at 140 us).
// Weights stay LANE-VARYING global loads (vmcnt path) — R5/R7 rule: a
// wave-uniform global operand becomes s_load (out-of-order) and forces
// lgkmcnt(0) drains against ds_read. Do not "simplify" that away.
// ---------------------------------------------------------------------------
__global__ __launch_bounds__(512, 4)
void mlp_hist(const float* __restrict__ x,
              const float* __restrict__ W1a, const float* __restrict__ b1a,
              const float* __restrict__ W2a, const float* __restrict__ b2a,
              const float* __restrict__ W1b, const float* __restrict__ b1b,
              const float* __restrict__ W2b, const float* __restrict__ b2b,
              float* __restrict__ qq,
              const float* __restrict__ rij, const int* __restrict__ dst,
              int* __restrict__ deg) {
  if (blockIdx.x >= MLP_BLOCKS) {
    // ---- histogram part ----
    const int e = (blockIdx.x - MLP_BLOCKS) * 512 + threadIdx.x;
    if (e < E_EDGES && rij[e] < CUTOFF) atomicAdd(&deg[dst[e]], 1);
    return;
  }

  __shared__ float sX[64 * XPAD];   // 33 KB; x tile, then h overlay

  const int bid = blockIdx.x;
  const int br  = (bid >= MLP_ROWBLOCKS) ? 1 : 0;
  const int rb  = (bid - br * MLP_ROWBLOCKS) * 64;

  const float* __restrict__ W1 = br ? W1b : W1a;
  const float* __restrict__ b1 = br ? b1b : b1a;
  const float* __restrict__ W2 = br ? W2b : W2a;
  const float* __restrict__ b2 = br ? b2b : b2a;

  const int t = threadIdx.x;
  const int l = t & 63;
  const int w = t >> 6;

  // ---- stage x[rb..rb+63][0..127] -> sX (coalesced 128B segments) ----
  {
    const int row = t >> 3;            // 0..63
    const int kq  = t & 7;             // 0..7
    const int rowG = min(rb + row, N_NODES - 1);
    const float* xp = x + (size_t)rowG * F_DIM;
#pragma unroll
    for (int p = 0; p < 4; ++p) {
      const int k0 = kq * 4 + p * 32;
      *(float4*)&sX[row * XPAD + k0] = *(const float4*)&xp[k0];
    }
  }
  __syncthreads();

  // ---- layer 1: lane = (group g: 4 rows) x (cols cb+32j, j=0..3) ----
  const int cb = l & 31;
  const int g  = (w << 1) + (l >> 5);   // 0..15
  const int r0 = g * 4;                 // block-local first row

  float acc[4][4];
#pragma unroll
  for (int j = 0; j < 4; ++j) {
    const float bj = b1[cb + 32 * j];
#pragma unroll
    for (int r = 0; r < 4; ++r) acc[r][j] = bj;
  }
  {
    const float* xrow = sX + r0 * XPAD;
#pragma unroll 2
    for (int k4 = 0; k4 < 32; ++k4) {
      float4 xv[4];
#pragma unroll
      for (int r = 0; r < 4; ++r)
        xv[r] = *(const float4*)&xrow[r * XPAD + k4 * 4];   // <=2 addrs/instr
#pragma unroll
      for (int kk = 0; kk < 4; ++kk) {
        const int k = k4 * 4 + kk;
        float wv[4];
#pragma unroll
        for (int j = 0; j < 4; ++j)
          wv[j] = W1[(size_t)k * F_DIM + cb + 32 * j];      // 128B coalesced
#pragma unroll
        for (int r = 0; r < 4; ++r) {
          const float xs = (kk == 0) ? xv[r].x : (kk == 1) ? xv[r].y
                         : (kk == 2) ? xv[r].z : xv[r].w;
#pragma unroll
          for (int j = 0; j < 4; ++j)
            acc[r][j] = fmaf(xs, wv[j], acc[r][j]);
        }
      }
    }
  }

  __syncthreads();                 // all waves done reading sX as x
#pragma unroll
  for (int r = 0; r < 4; ++r)
#pragma unroll
    for (int j = 0; j < 4; ++j)    // h overlay (<=2 lanes/bank = free)
      sX[(r0 + r) * XPAD + cb + 32 * j] = swishf(acc[r][j]);
  __syncthreads();

  // ---- layer 2: lane = col c2 (=cb), same 4-row group ----
  float acc2[4];
  {
    const float b2c = b2[cb];
#pragma unroll
    for (int r = 0; r < 4; ++r) acc2[r] = b2c;
  }
  {
    const float* hrow = sX + r0 * XPAD;
#pragma unroll 2
    for (int k4 = 0; k4 < 32; ++k4) {
      float4 hv[4];
#pragma unroll
      for (int r = 0; r < 4; ++r)
        hv[r] = *(const float4*)&hrow[r * XPAD + k4 * 4];
#pragma unroll
      for (int kk = 0; kk < 4; ++kk) {
        const float wv = W2[(size_t)(k4 * 4 + kk) * D_DIM + cb];
#pragma unroll
        for (int r = 0; r < 4; ++r) {
          const float hs = (kk == 0) ? hv[r].x : (kk == 1) ? hv[r].y
                         : (kk == 2) ? hv[r].z : hv[r].w;
          acc2[r] = fmaf(hs, wv, acc2[r]);
        }
      }
    }
  }
#pragma unroll
  for (int r = 0; r < 4; ++r) {
    const int row = rb + r0 + r;
    if (row < N_NODES) qq[(size_t)row * 64 + 2 * cb + br] = swishf(acc2[r]);
  }
}

// --- 3-phase coalesced scan over deg[N] -> row_start[N+1], cursor[N] ---
__global__ __launch_bounds__(256)
void scan_blocksum(const int* __restrict__ deg, int* __restrict__ part) {
  __shared__ int red[256];
  const int t = threadIdx.x;
  const int i = blockIdx.x * 256 + t;
  red[t] = (i < N_NODES) ? deg[i] : 0;
  __syncthreads();
#pragma unroll
  for (int off = 128; off > 0; off >>= 1) {
    if (t < off) red[t] += red[t + off];
    __syncthreads();
  }
  if (t == 0) part[blockIdx.x] = red[0];
}

__global__ __launch_bounds__(256)
void scan_partials(int* __restrict__ part, int* __restrict__ row_start) {
  __shared__ int s[256];
  const int t = threadIdx.x;
  const int v = (t < SCAN_BLOCKS) ? part[t] : 0;
  s[t] = v;
  __syncthreads();
  for (int off = 1; off < 256; off <<= 1) {
    const int u = (t >= off) ? s[t - off] : 0;
    __syncthreads();
    s[t] += u;
    __syncthreads();
  }
  if (t < SCAN_BLOCKS) part[t] = s[t] - v;          // exclusive block offset
  if (t == 255) row_start[N_NODES] = s[255];        // grand total
}

__global__ __launch_bounds__(256)
void scan_write(const int* __restrict__ deg, const int* __restrict__ part,
                int* __restrict__ row_start, int* __restrict__ cursor) {
  __shared__ int s[256];
  const int t = threadIdx.x;
  const int i = blockIdx.x * 256 + t;
  const int v = (i < N_NODES) ? deg[i] : 0;
  s[t] = v;
  __syncthreads();
  for (int off = 1; off < 256; off <<= 1) {
    const int u = (t >= off) ? s[t - off] : 0;
    __syncthreads();
    s[t] += u;
    __syncthreads();
  }
  const int excl = s[t] - v + part[blockIdx.x];
  if (i < N_NODES) { row_start[i] = excl; cursor[i] = excl; }
}

// Reorder surviving edges into per-dst contiguous records:
// rec = (c*vx, c*vy, c*vz, bitcast(src))
__global__ __launch_bounds__(256)
void edge_reorder(const float* __restrict__ rij, const float* __restrict__ vij,
                  const int* __restrict__ src, const int* __restrict__ dst,
                  int* __restrict__ cursor, float4* __restrict__ recs) {
  const int e = blockIdx.x * 256 + threadIdx.x;
  if (e >= E_EDGES) return;
  const float r = rij[e];
  if (r >= CUTOFF) return;
  const float c = 0.5f * (cosf(r * (PI_F / CUTOFF)) + 1.0f);
  const int pos = atomicAdd(&cursor[dst[e]], 1);
  recs[pos] = make_float4(c * vij[3 * e + 0], c * vij[3 * e + 1],
                          c * vij[3 * e + 2], __int_as_float(src[e]));
}

// ---------------------------------------------------------------------------
// Gather + cross + mix: 32 lanes per node (one per d). 4-edge batches to
// break the rec->q dependent-load chain; qq is (q,q2) interleaved float2.
// ---------------------------------------------------------------------------
__global__ __launch_bounds__(256)
void gather_out(const int* __restrict__ row_start, const float4* __restrict__ recs,
                const float2* __restrict__ qq,
                const float* __restrict__ w_mix, const float* __restrict__ b_mix,
                float* __restrict__ out) {
  const int tid = blockIdx.x * 256 + threadIdx.x;  // = n*32 + d
  const int n = tid >> 5;
  const int d = tid & 31;
  if (n >= N_NODES) return;

  const int s0 = row_start[n];
  const int s1 = row_start[n + 1];

  float ax = 0.f, ay = 0.f, az = 0.f, bx = 0.f, by = 0.f, bz = 0.f;
  for (int i = s0; i < s1; i += 4) {
    const int i1 = min(i + 1, s1 - 1);
    const int i2 = min(i + 2, s1 - 1);
    const int i3 = min(i + 3, s1 - 1);
    float4 rc0 = recs[i];
    float4 rc1 = recs[i1];
    float4 rc2 = recs[i2];
    float4 rc3 = recs[i3];
    float2 p0 = qq[__float_as_int(rc0.w) * 32 + d];
    float2 p1 = qq[__float_as_int(rc1.w) * 32 + d];
    float2 p2 = qq[__float_as_int(rc2.w) * 32 + d];
    float2 p3 = qq[__float_as_int(rc3.w) * 32 + d];
    const float m1 = (i + 1 < s1) ? 1.f : 0.f;
    const float m2 = (i + 2 < s1) ? 1.f : 0.f;
    const float m3 = (i + 3 < s1) ? 1.f : 0.f;
    p1.x *= m1; p1.y *= m1;
    p2.x *= m2; p2.y *= m2;
    p3.x *= m3; p3.y *= m3;

    ax += rc0.x * p0.x + rc1.x * p1.x + rc2.x * p2.x + rc3.x * p3.x;
    ay += rc0.y * p0.x + rc1.y * p1.x + rc2.y * p2.x + rc3.y * p3.x;
    az += rc0.z * p0.x + rc1.z * p1.x + rc2.z * p2.x + rc3.z * p3.x;
    bx += rc0.x * p0.y + rc1.x * p1.y + rc2.x * p2.y + rc3.x * p3.y;
    by += rc0.y * p0.y + rc1.y * p1.y + rc2.y * p2.y + rc3.y * p3.y;
    bz += rc0.z * p0.y + rc1.z * p1.y + rc2.z * p2.y + rc3.z * p3.y;
  }

  const float cx = ay * bz - az * by;
  const float cy = az * bx - ax * bz;
  const float cz = ax * by - ay * bx;

  const float w0 = w_mix[0], w1 = w_mix[1], w2 = w_mix[2];
  const float bm = b_mix[0];

  const size_t base = (size_t)tid * 3;
  out[base + 0] = ax * w0 + bx * w1 + cx * w2 + bm;
  out[base + 1] = ay * w0 + by * w1 + cy * w2 + bm;
  out[base + 2] = az * w0 + bz * w1 + cz * w2 + bm;
}

// ---------------------------------------------------------------------------
extern "C" void kernel_launch(void* const* d_in, const int* in_sizes, int n_in,
                              void* d_out, int out_size, void* d_ws, size_t ws_size,
                              hipStream_t stream) {
  const float* x     = (const float*)d_in[0];
  const float* rij   = (const float*)d_in[1];
  const float* vij   = (const float*)d_in[2];
  const int*   src   = (const int*)  d_in[3];
  const int*   dst   = (const int*)  d_in[4];
  const float* W1    = (const float*)d_in[5];
  const float* b1    = (const float*)d_in[6];
  const float* W2    = (const float*)d_in[7];
  const float* b2    = (const float*)d_in[8];
  const float* W1b   = (const float*)d_in[9];
  const float* b1b   = (const float*)d_in[10];
  const float* W2b   = (const float*)d_in[11];
  const float* b2b   = (const float*)d_in[12];
  const float* w_mix = (const float*)d_in[13];
  const float* b_mix = (const float*)d_in[14];
  float* out = (float*)d_out;

  // Workspace: recs [E f4] | qq [N*64] | deg [N] | cursor [N] | row_start [N+1] | part [256]
  float4* recs   = (float4*)d_ws;
  float* qq      = (float*)(recs + E_EDGES);
  int* deg       = (int*)(qq + (size_t)N_NODES * 64);
  int* cursor    = deg + N_NODES;
  int* row_start = cursor + N_NODES;
  int* part      = row_start + N_NODES + 1;

  hipMemsetAsync(deg, 0, sizeof(int) * N_NODES, stream);

  mlp_hist<<<MLP_BLOCKS + HIST_BLOCKS, 512, 0, stream>>>(
      x, W1, b1, W2, b2, W1b, b1b, W2b, b2b, qq, rij, dst, deg);

  scan_blocksum<<<SCAN_BLOCKS, 256, 0, stream>>>(deg, part);
  scan_partials<<<1, 256, 0, stream>>>(part, row_start);
  scan_write<<<SCAN_BLOCKS, 256, 0, stream>>>(deg, part, row_start, cursor);

  const int eb = (E_EDGES + 255) / 256;
  edge_reorder<<<eb, 256, 0, stream>>>(rij, vij, src, dst, cursor, recs);

  gather_out<<<(N_NODES * D_DIM) / 256, 256, 0, stream>>>(
      row_start, recs, (const float2*)qq, w_mix, b_mix, out);
}